// Round 5
// baseline (537.471 us; speedup 1.0000x reference)
//
#include <hip/hip_runtime.h>
#include <math.h>

// Qwen3 MoE gate: logits = hidden @ W_gate^T ; softmax ; top-8 ; renorm.
// Outputs (flat f32): sel_w [T*8], sel_idx-as-float [T*8], logits [T*64].
//
// R5: one fused kernel. 8x8 per-thread tile (0.25 LDS-floats/FMA — the max
// register reuse under the 64-token/64-expert block cap), 8-way k-split
// across waves (2 waves/SIMD at grid=256), per-wave private [64][20]-padded
// LDS tiles (pad 20 => ds_read_b128 start banks 20*tg%32 all-distinct =
// conflict-free, 8-way broadcast across the other lane axis), T14 staging
// (global loads issued before compute, b128 LDS writes after), LDS tree
// reduce + fused logits-store / top-9 / flag epilogue. fp64 fixup for
// near-tie tokens (TAU) as in R3.

#define HDIM 2048
#define NEXP 64
#define TOPK 8
#define NSCAN 9
#define TAU  2.5e-4f

#define KSPLIT 8
#define KWIN  (HDIM / KSPLIT)   // 256 k per wave
#define BK    16                // k per staged chunk
#define NCH   (KWIN / BK)       // 16 chunks
#define TROW  20                // tile row stride (floats): 16 + 4 pad
#define TILEF (64 * TROW)       // 1280 floats per tile
#define WVF   (2 * TILEF)       // 2560 floats per wave (H + W)
#define RROW  68                // reduce row stride (floats)
#define RSL   (64 * RROW)       // 4352 floats per reduce slice

__global__ __launch_bounds__(512, 2) void gate_fused(
    const float* __restrict__ hidden,   // [T, 2048]
    const float* __restrict__ wgate,    // [64, 2048]
    float* __restrict__ logits,         // [T, 64]
    float* __restrict__ selw,           // [T, 8]
    float* __restrict__ selidx,         // [T, 8]
    int* __restrict__ cnt,
    int* __restrict__ list)
{
    __shared__ float lds[KSPLIT * WVF];   // 20480 floats = 80 KiB

    const int tid  = threadIdx.x;
    const int lane = tid & 63;
    const int wv   = __builtin_amdgcn_readfirstlane(tid >> 6);
    const int tg   = lane & 7;     // token group: tokens tg + 8i
    const int eg   = lane >> 3;    // expert group: experts eg + 8j
    const size_t tokBase = (size_t)blockIdx.x * 64;
    const int kw   = wv * KWIN;

    float* Ht = &lds[wv * WVF];
    float* Wt = Ht + TILEF;

    float acc[8][8];
#pragma unroll
    for (int i = 0; i < 8; ++i)
#pragma unroll
        for (int j = 0; j < 8; ++j) acc[i][j] = 0.f;

    // staging map: float4 g = p*64+lane -> row p*16+(lane>>2), c4 = lane&3.
    const int srow = lane >> 2;
    const int sc4  = lane & 3;

    float4 hreg[4], wreg[4];

    // ---- prologue: chunk 0
#pragma unroll
    for (int p = 0; p < 4; ++p) {
        hreg[p] = *reinterpret_cast<const float4*>(
            &hidden[(tokBase + p * 16 + srow) * HDIM + kw + sc4 * 4]);
        wreg[p] = *reinterpret_cast<const float4*>(
            &wgate[(size_t)(p * 16 + srow) * HDIM + kw + sc4 * 4]);
    }
#pragma unroll
    for (int p = 0; p < 4; ++p) {
        *reinterpret_cast<float4*>(&Ht[(p * 16 + srow) * TROW + sc4 * 4]) = hreg[p];
        *reinterpret_cast<float4*>(&Wt[(p * 16 + srow) * TROW + sc4 * 4]) = wreg[p];
    }

    for (int c = 0; c < NCH; ++c) {
        // issue next chunk's global loads early (land under ~2000cy of FMA)
        if (c + 1 < NCH) {
            const int kn = kw + (c + 1) * BK;
#pragma unroll
            for (int p = 0; p < 4; ++p) {
                hreg[p] = *reinterpret_cast<const float4*>(
                    &hidden[(tokBase + p * 16 + srow) * HDIM + kn + sc4 * 4]);
                wreg[p] = *reinterpret_cast<const float4*>(
                    &wgate[(size_t)(p * 16 + srow) * HDIM + kn + sc4 * 4]);
            }
        }

        // compute chunk c: 4 k4-steps, 16 conflict-free b128 reads each
#pragma unroll
        for (int kk = 0; kk < BK; kk += 4) {
            float4 h4[8], w4[8];
#pragma unroll
            for (int i = 0; i < 8; ++i)
                h4[i] = *reinterpret_cast<const float4*>(&Ht[(tg + 8 * i) * TROW + kk]);
#pragma unroll
            for (int j = 0; j < 8; ++j)
                w4[j] = *reinterpret_cast<const float4*>(&Wt[(eg + 8 * j) * TROW + kk]);
#pragma unroll
            for (int i = 0; i < 8; ++i)
#pragma unroll
                for (int j = 0; j < 8; ++j) {
                    acc[i][j] += h4[i].x * w4[j].x;
                    acc[i][j] += h4[i].y * w4[j].y;
                    acc[i][j] += h4[i].z * w4[j].z;
                    acc[i][j] += h4[i].w * w4[j].w;
                }
        }

        // write staged chunk c+1 (same wave: DS ops ordered after the reads)
        if (c + 1 < NCH) {
#pragma unroll
            for (int p = 0; p < 4; ++p) {
                *reinterpret_cast<float4*>(&Ht[(p * 16 + srow) * TROW + sc4 * 4]) = hreg[p];
                *reinterpret_cast<float4*>(&Wt[(p * 16 + srow) * TROW + sc4 * 4]) = wreg[p];
            }
        }
    }

    // ---- tree-reduce 8 k-partials into wave 0 (reuse lds) ----
    __syncthreads();
    if (wv >= 4) {
        float* R = &lds[(wv - 4) * RSL];
#pragma unroll
        for (int i = 0; i < 8; ++i)
#pragma unroll
            for (int j = 0; j < 8; ++j)
                R[(tg + 8 * i) * RROW + eg + 8 * j] = acc[i][j];
    }
    __syncthreads();
    if (wv < 4) {
        const float* R = &lds[wv * RSL];
#pragma unroll
        for (int i = 0; i < 8; ++i)
#pragma unroll
            for (int j = 0; j < 8; ++j)
                acc[i][j] += R[(tg + 8 * i) * RROW + eg + 8 * j];
    }
    __syncthreads();
    if (wv == 2 || wv == 3) {
        float* R = &lds[(wv - 2) * RSL];
#pragma unroll
        for (int i = 0; i < 8; ++i)
#pragma unroll
            for (int j = 0; j < 8; ++j)
                R[(tg + 8 * i) * RROW + eg + 8 * j] = acc[i][j];
    }
    __syncthreads();
    if (wv < 2) {
        const float* R = &lds[wv * RSL];
#pragma unroll
        for (int i = 0; i < 8; ++i)
#pragma unroll
            for (int j = 0; j < 8; ++j)
                acc[i][j] += R[(tg + 8 * i) * RROW + eg + 8 * j];
    }
    __syncthreads();
    if (wv == 1) {
        float* R = &lds[0];
#pragma unroll
        for (int i = 0; i < 8; ++i)
#pragma unroll
            for (int j = 0; j < 8; ++j)
                R[(tg + 8 * i) * RROW + eg + 8 * j] = acc[i][j];
    }
    __syncthreads();
    if (wv == 0) {
        float* R = &lds[0];
#pragma unroll
        for (int i = 0; i < 8; ++i)
#pragma unroll
            for (int j = 0; j < 8; ++j) {
                acc[i][j] += R[(tg + 8 * i) * RROW + eg + 8 * j];
                R[(tg + 8 * i) * RROW + eg + 8 * j] = acc[i][j];  // final tile
            }
    }
    __syncthreads();

    // ---- fused epilogue ----
    if (wv == 0) {
        // coalesced logits store: 16 instrs x (4 rows x 16 lanes x 16B)
#pragma unroll
        for (int p = 0; p < 16; ++p) {
            const int row = p * 4 + (lane >> 4);
            const int col = 4 * (lane & 15);
            const float4 v4 = *reinterpret_cast<const float4*>(&lds[row * RROW + col]);
            *reinterpret_cast<float4*>(&logits[(tokBase + row) * NEXP + col]) = v4;
        }
    } else if (wv == 1) {
        // top-9 scan, lane = token
        const int t = lane;
        float v[NEXP];
#pragma unroll
        for (int q = 0; q < 16; ++q) {
            const float4 f = *reinterpret_cast<const float4*>(&lds[t * RROW + 4 * q]);
            v[4 * q + 0] = f.x; v[4 * q + 1] = f.y;
            v[4 * q + 2] = f.z; v[4 * q + 3] = f.w;
        }

        float bv[NSCAN];
        int   bidx[NSCAN];
        unsigned long long used = 0ull;
#pragma unroll
        for (int k = 0; k < NSCAN; ++k) {
            float best = -INFINITY;
            int   bi   = 0;
#pragma unroll
            for (int i = 0; i < NEXP; ++i) {
                const bool avail = ((used >> i) & 1ull) == 0ull;
                if (avail && v[i] > best) { best = v[i]; bi = i; }
            }
            bv[k]   = best;
            bidx[k] = bi;
            used |= (1ull << bi);
        }

        float ming = bv[0] - bv[1];
#pragma unroll
        for (int k = 1; k < NSCAN - 1; ++k) ming = fminf(ming, bv[k] - bv[k + 1]);
        const size_t gt = tokBase + t;
        if (ming < TAU) {
            const int pos = atomicAdd(cnt, 1);   // order-free: fixup is per-token
            list[pos] = (int)gt;
        }

        const float m = bv[0];
        float ek[TOPK];
        float s = 0.f;
#pragma unroll
        for (int k = 0; k < TOPK; ++k) { ek[k] = expf(bv[k] - m); s += ek[k]; }
        const float inv = 1.0f / s;
#pragma unroll
        for (int k = 0; k < TOPK; ++k) {
            selw[gt * TOPK + k]   = ek[k] * inv;
            selidx[gt * TOPK + k] = (float)bidx[k];
        }
    }
}

// ---------------- fp64 re-dot + exact top-8 for flagged tokens ------------
__global__ __launch_bounds__(256) void gate_fixup_f64(
    const float* __restrict__ hidden,
    const float* __restrict__ wgate,
    const int* __restrict__ cnt,
    const int* __restrict__ list,
    float* __restrict__ selw,
    float* __restrict__ selidx)
{
    const int lane   = threadIdx.x & 63;
    const int waveId = (blockIdx.x * blockDim.x + threadIdx.x) >> 6;
    const int nWaves = (gridDim.x * blockDim.x) >> 6;
    const int n      = *cnt;

    for (int i = waveId; i < n; i += nWaves) {
        const int t = list[i];
        const float* hrow = &hidden[(size_t)t * HDIM];
        const float* wrow = &wgate[(size_t)lane * HDIM];

        double a0 = 0.0, a1 = 0.0, a2 = 0.0, a3 = 0.0;
#pragma unroll 2
        for (int k = 0; k < HDIM; k += 16) {
            const float4 h0 = *reinterpret_cast<const float4*>(&hrow[k +  0]);
            const float4 h1 = *reinterpret_cast<const float4*>(&hrow[k +  4]);
            const float4 h2 = *reinterpret_cast<const float4*>(&hrow[k +  8]);
            const float4 h3 = *reinterpret_cast<const float4*>(&hrow[k + 12]);
            const float4 w0 = *reinterpret_cast<const float4*>(&wrow[k +  0]);
            const float4 w1 = *reinterpret_cast<const float4*>(&wrow[k +  4]);
            const float4 w2 = *reinterpret_cast<const float4*>(&wrow[k +  8]);
            const float4 w3 = *reinterpret_cast<const float4*>(&wrow[k + 12]);
            a0 += (double)h0.x * w0.x + (double)h0.y * w0.y
                + (double)h0.z * w0.z + (double)h0.w * w0.w;
            a1 += (double)h1.x * w1.x + (double)h1.y * w1.y
                + (double)h1.z * w1.z + (double)h1.w * w1.w;
            a2 += (double)h2.x * w2.x + (double)h2.y * w2.y
                + (double)h2.z * w2.z + (double)h2.w * w2.w;
            a3 += (double)h3.x * w3.x + (double)h3.y * w3.y
                + (double)h3.z * w3.z + (double)h3.w * w3.w;
        }
        double v = (a0 + a1) + (a2 + a3);
        int   id = lane;

        double bv[TOPK];
        int    bidx[TOPK];
#pragma unroll
        for (int p = 0; p < TOPK; ++p) {
            double mv = v;
            int    mi = id;
#pragma unroll
            for (int off = 32; off >= 1; off >>= 1) {
                const double ov = __shfl_xor(mv, off);
                const int    oi = __shfl_xor(mi, off);
                if (ov > mv || (ov == mv && oi < mi)) { mv = ov; mi = oi; }
            }
            bv[p]   = mv;
            bidx[p] = mi;
            if (id == mi) v = -INFINITY;
        }

        if (lane == 0) {
            float ek[TOPK];
            float s = 0.f;
#pragma unroll
            for (int p = 0; p < TOPK; ++p) {
                ek[p] = expf((float)(bv[p] - bv[0]));
                s += ek[p];
            }
            const float inv = 1.0f / s;
#pragma unroll
            for (int p = 0; p < TOPK; ++p) {
                selw[(size_t)t * TOPK + p]   = ek[p] * inv;
                selidx[(size_t)t * TOPK + p] = (float)bidx[p];
            }
        }
    }
}

extern "C" void kernel_launch(void* const* d_in, const int* in_sizes, int n_in,
                              void* d_out, int out_size, void* d_ws, size_t ws_size,
                              hipStream_t stream) {
    const float* hidden = (const float*)d_in[0];   // [4,4096,2048] f32
    const float* wgate  = (const float*)d_in[1];   // [64,2048] f32

    const int T = in_sizes[0] / HDIM;              // 16384 tokens

    float* out    = (float*)d_out;
    float* selw   = out;                           // T*8
    float* selidx = out + (size_t)T * TOPK;        // T*8
    float* logits = out + (size_t)2 * T * TOPK;    // T*64

    int* cnt  = (int*)d_ws;
    int* list = (int*)d_ws + 64;

    hipMemsetAsync(d_ws, 0, 256, stream);

    gate_fused<<<T / 64, 512, 0, stream>>>(hidden, wgate, logits,
                                           selw, selidx, cnt, list);
    gate_fixup_f64<<<256, 256, 0, stream>>>(hidden, wgate, cnt, list, selw, selidx);
}